// Round 6
// baseline (425.805 us; speedup 1.0000x reference)
//
#include <hip/hip_runtime.h>
#include <math.h>

// Problem constants (B=2, T=2048, C=2048, 16 heads, 4 KV heads, HD=128)
#define NB 2
#define T_SEQ 2048
#define C_DIM 2048
#define NH 16
#define NKV 4
#define HD 128
#define KV_DIM (NKV * HD)   // 512
#define M_ROWS (NB * T_SEQ) // 4096

typedef short bf16w8 __attribute__((ext_vector_type(8)));   // MFMA A/B frag (8 bf16)
typedef float f32x4 __attribute__((ext_vector_type(4)));    // 16x16 C/D frag
typedef float f32x16 __attribute__((ext_vector_type(16)));  // 32x32 C/D frag
typedef unsigned short u16x8 __attribute__((ext_vector_type(8)));
typedef unsigned short u16x4 __attribute__((ext_vector_type(4)));

__device__ __forceinline__ unsigned short f2bf(float x) {
  union { float f; unsigned u; } v; v.f = x;
  return (unsigned short)((v.u + 0x7FFFu + ((v.u >> 16) & 1u)) >> 16);
}

// packed bf16 pair: low = lo, high = hi
__device__ __forceinline__ unsigned int cvt_pk_bf16(float lo, float hi) {
  unsigned int r;
  asm("v_cvt_pk_bf16_f32 %0, %1, %2" : "=v"(r) : "v"(lo), "v"(hi));
  return r;
}

__device__ __forceinline__ float wave_reduce_sum(float v) {
#pragma unroll
  for (int off = 32; off > 0; off >>= 1) v += __shfl_xor(v, off, 64);
  return v;
}

// ---------------------------------------------------------------------------
// fp32 -> bf16 bulk convert (16B stores). n8 = elems/8, sizes divisible by 8.
// ---------------------------------------------------------------------------
__global__ __launch_bounds__(256) void cvt_f32_bf16(
    const float* __restrict__ in, unsigned short* __restrict__ out, int n8) {
  int i = blockIdx.x * 256 + threadIdx.x;
  if (i >= n8) return;
  float4 a = ((const float4*)in)[i * 2];
  float4 b = ((const float4*)in)[i * 2 + 1];
  u16x8 o;
  o[0] = f2bf(a.x); o[1] = f2bf(a.y); o[2] = f2bf(a.z); o[3] = f2bf(a.w);
  o[4] = f2bf(b.x); o[5] = f2bf(b.y); o[6] = f2bf(b.z); o[7] = f2bf(b.w);
  *(u16x8*)(out + (size_t)i * 8) = o;
}

// ---------------------------------------------------------------------------
// RoPE cos/sin tables: [T][64] each. theta = 500000.
// ---------------------------------------------------------------------------
__global__ void rope_tables(float* __restrict__ cost, float* __restrict__ sint) {
  int t = blockIdx.x;
  int i = threadIdx.x; // 0..63
  float inv_freq = powf(500000.0f, -(float)i / 64.0f);
  float ang = (float)t * inv_freq;
  cost[t * 64 + i] = cosf(ang);
  sint[t * 64 + i] = sinf(ang);
}

// ---------------------------------------------------------------------------
// GEMM (m97 structure): C[M][N] = A[M][K] * W[N][K]^T, A/W bf16, C fp32.
// 128x128 tile, BK=64, 4 waves (2x2), 4x4 mfma_16x16x32 per wave.
// Staging via global_load_lds width=16 into LINEAR LDS [128][64].
// ---------------------------------------------------------------------------
__global__ __launch_bounds__(256) void gemm_lds_bf16(
    const unsigned short* __restrict__ A, const unsigned short* __restrict__ W,
    float* __restrict__ C, int M, int N, int K) {
  __shared__ __align__(16) unsigned short As[128 * 64];
  __shared__ __align__(16) unsigned short Ws[128 * 64];
  int tid = threadIdx.x;
  int lane = tid & 63;
  int w = tid >> 6;
  int wr = w >> 1, wc = w & 1;
  int l15 = lane & 15, l4 = lane >> 4;

  int segrow = lane >> 3;
  int segk = (lane & 7) * 8;
  const unsigned short* Ag =
      A + (size_t)(blockIdx.y * 128 + w * 32 + segrow) * K + segk;
  const unsigned short* Wg =
      W + (size_t)(blockIdx.x * 128 + w * 32 + segrow) * K + segk;

  f32x4 zero = {0.f, 0.f, 0.f, 0.f};
  f32x4 acc[4][4];
#pragma unroll
  for (int m = 0; m < 4; ++m)
#pragma unroll
    for (int n = 0; n < 4; ++n) acc[m][n] = zero;

  for (int k0 = 0; k0 < K; k0 += 64) {
    __syncthreads();  // previous iteration's LDS reads complete
#pragma unroll
    for (int i = 0; i < 4; ++i) {
      __builtin_amdgcn_global_load_lds(
          (const __attribute__((address_space(1))) void*)(Ag + k0 + (size_t)i * 8 * K),
          (__attribute__((address_space(3))) void*)&As[(w * 32 + i * 8) * 64],
          16, 0, 0);
      __builtin_amdgcn_global_load_lds(
          (const __attribute__((address_space(1))) void*)(Wg + k0 + (size_t)i * 8 * K),
          (__attribute__((address_space(3))) void*)&Ws[(w * 32 + i * 8) * 64],
          16, 0, 0);
    }
    __syncthreads();

    bf16w8 af[2][4], bw[2][4];
#pragma unroll
    for (int kk = 0; kk < 2; ++kk) {
#pragma unroll
      for (int m = 0; m < 4; ++m)
        af[kk][m] = *(const bf16w8*)&As[(wr * 64 + m * 16 + l15) * 64 + kk * 32 + l4 * 8];
#pragma unroll
      for (int n = 0; n < 4; ++n)
        bw[kk][n] = *(const bf16w8*)&Ws[(wc * 64 + n * 16 + l15) * 64 + kk * 32 + l4 * 8];
    }
#pragma unroll
    for (int kk = 0; kk < 2; ++kk)
#pragma unroll
      for (int m = 0; m < 4; ++m)
#pragma unroll
        for (int n = 0; n < 4; ++n)
          acc[m][n] = __builtin_amdgcn_mfma_f32_16x16x32_bf16(
              af[kk][m], bw[kk][n], acc[m][n], 0, 0, 0);
  }

#pragma unroll
  for (int m = 0; m < 4; ++m)
#pragma unroll
    for (int n = 0; n < 4; ++n)
#pragma unroll
      for (int j = 0; j < 4; ++j) {
        int row = blockIdx.y * 128 + wr * 64 + m * 16 + l4 * 4 + j;
        int col = blockIdx.x * 128 + wc * 64 + n * 16 + l15;
        C[(size_t)row * N + col] = acc[m][n][j];
      }
}

// ---------------------------------------------------------------------------
// Per-head RMSNorm + RoPE, fp32 in -> bf16 out (scale folded for Q).
// ---------------------------------------------------------------------------
__global__ __launch_bounds__(256) void norm_rope_bf16(
    const float* __restrict__ X, unsigned short* __restrict__ Y,
    const float* __restrict__ w, const float* __restrict__ cost,
    const float* __restrict__ sint, int nheads, int istride, int ostride,
    float oscale) {
  int wid = (blockIdx.x * 256 + threadIdx.x) >> 6;
  int lane = threadIdx.x & 63;
  int h = wid % nheads;
  int bt = wid / nheads;
  int t = bt & (T_SEQ - 1);
  const float* row = X + (size_t)bt * istride + h * HD;
  float x1 = row[lane];
  float x2 = row[lane + 64];
  float ss = wave_reduce_sum(x1 * x1 + x2 * x2);
  float r = rsqrtf(ss * (1.0f / 128.0f) + 1e-6f);
  x1 = x1 * r * w[lane];
  x2 = x2 * r * w[lane + 64];
  float c = cost[t * 64 + lane];
  float s = sint[t * 64 + lane];
  unsigned short* yrow = Y + (size_t)bt * ostride + h * HD;
  yrow[lane]      = f2bf((x1 * c - x2 * s) * oscale);
  yrow[lane + 64] = f2bf((x2 * c + x1 * s) * oscale);
}

// ---------------------------------------------------------------------------
// V transpose: Vp fp32 rows (stride istride) -> Vt bf16 [(b*512+c)][T].
// ---------------------------------------------------------------------------
__global__ __launch_bounds__(256) void transpose_v(
    const float* __restrict__ Vp, unsigned short* __restrict__ Vt, int istride) {
  __shared__ float tile[64][65];
  int bt_tile = blockIdx.x;           // 0..63  (b*32 + ttile)
  int ct = blockIdx.y;                // 0..7
  int b = bt_tile >> 5;
  int t0 = (bt_tile & 31) * 64;
  int c0 = ct * 64;
  int tid = threadIdx.x;
  int r = tid >> 4;                   // 0..15
  int c4 = (tid & 15) * 4;
#pragma unroll
  for (int p = 0; p < 4; ++p) {
    int row = r + p * 16;
    float4 v = *(const float4*)&Vp[(size_t)(b * T_SEQ + t0 + row) * istride + c0 + c4];
    tile[row][c4] = v.x; tile[row][c4 + 1] = v.y;
    tile[row][c4 + 2] = v.z; tile[row][c4 + 3] = v.w;
  }
  __syncthreads();
#pragma unroll
  for (int p = 0; p < 4; ++p) {
    int drow = r + p * 16;            // local col index = output row
    int cg = c0 + drow;
    u16x4 o;
    o[0] = f2bf(tile[c4 + 0][drow]);
    o[1] = f2bf(tile[c4 + 1][drow]);
    o[2] = f2bf(tile[c4 + 2][drow]);
    o[3] = f2bf(tile[c4 + 3][drow]);
    *(u16x4*)&Vt[(size_t)(b * KV_DIM + cg) * T_SEQ + t0 + c4] = o;
  }
}

// ---------------------------------------------------------------------------
// Causal GQA flash attention v5: round-4 verified per-iteration body
// (swapped-operand 32x32x16 MFMA, in-register softmax, defer-max, exp2,
// cvt_pk+shfl P^T exchange) + flash-decoding SPLIT-K for 4x occupancy.
// Block = 4 waves, ALL on one (b,h,qtile) task; wave w takes key blocks
// kt ≡ w (mod 4). Partials (m,l,acc) merged via LDS pairwise tree.
// Each block processes mirror-paired tasks jj then 63-jj (uniform work).
// 1024 blocks; pr=(bid&7)*128+(bid>>3) pins each (b,kvh) K/V to one XCD L2.
// S^T = mfma(A=K, B=Q): col=q=lane&31, row=key=(reg&3)+8*(reg>>2)+4*(lane>>5).
// ---------------------------------------------------------------------------
__global__ __launch_bounds__(256, 4) void attn_mfma4(
    const unsigned short* __restrict__ Qb, const unsigned short* __restrict__ Kb,
    const unsigned short* __restrict__ Vt, unsigned short* __restrict__ Ob) {
  __shared__ float cmb[2][64][66];  // [slot][lane][acc 0..63 | m | l]
  int lane = threadIdx.x & 63;
  int q31 = lane & 31;
  int hi = lane >> 5;
  int w = threadIdx.x >> 6;           // 0..3 (split-K slice)

  int bid = blockIdx.x;               // 0..1023
  int pr = (bid & 7) * 128 + (bid >> 3);  // pr>>7 = b*4+kvh : one group per XCD
  int jj = pr & 31;
  int h = (pr >> 5) & 15;
  int b = pr >> 9;
  int kvh = h >> 2;

  const unsigned short* kptr =
      Kb + ((size_t)(b * T_SEQ)) * KV_DIM + kvh * HD + hi * 8;
  const unsigned short* vptr =
      Vt + ((size_t)(b * KV_DIM + kvh * HD + q31)) * T_SEQ + hi * 8;

  for (int side = 0; side < 2; ++side) {
    int qtile = side ? (63 - jj) : jj;
    int q0 = qtile * 32;

    // Q fragments (B-operand): col=q=q31, k = kc*16 + hi*8 + j
    const unsigned short* qptr =
        Qb + ((size_t)(b * T_SEQ + q0 + q31)) * C_DIM + h * HD + hi * 8;
    bf16w8 qf[8];
#pragma unroll
    for (int kc = 0; kc < 8; ++kc) qf[kc] = *(const bf16w8*)(qptr + kc * 16);

    f32x16 acc[4];
#pragma unroll
    for (int dt = 0; dt < 4; ++dt)
#pragma unroll
      for (int r = 0; r < 16; ++r) acc[dt][r] = 0.f;
    float m = -INFINITY, l = 0.f;
    const int ktend = qtile;

    for (int kt = w; kt <= ktend; kt += 4) {
      // K fragments (A-operand): row=key_local=q31, k = kc*16 + hi*8 + j
      const unsigned short* krow = kptr + (size_t)(kt * 32 + q31) * KV_DIM;
      bf16w8 kf[8];
#pragma unroll
      for (int kc = 0; kc < 8; ++kc) kf[kc] = *(const bf16w8*)(krow + kc * 16);

      f32x16 s;
#pragma unroll
      for (int r = 0; r < 16; ++r) s[r] = 0.f;
      __builtin_amdgcn_s_setprio(1);
#pragma unroll
      for (int kc = 0; kc < 8; ++kc)
        s = __builtin_amdgcn_mfma_f32_32x32x16_bf16(kf[kc], qf[kc], s, 0, 0, 0);
      __builtin_amdgcn_s_setprio(0);

      // V^T fragments for this key block (independent of softmax -> overlap)
      bf16w8 vf[8];
#pragma unroll
      for (int dt = 0; dt < 4; ++dt)
#pragma unroll
        for (int kc = 0; kc < 2; ++kc)
          vf[dt * 2 + kc] = *(const bf16w8*)(vptr + (size_t)dt * 32 * T_SEQ +
                                             kt * 32 + kc * 16);

      if (kt == ktend) {  // diagonal: mask key > q
#pragma unroll
        for (int r = 0; r < 16; ++r) {
          int key = (r & 3) + 8 * (r >> 2) + 4 * hi;
          if (kt * 32 + key > q0 + q31) s[r] = -INFINITY;
        }
      }

      float tmax = s[0];
#pragma unroll
      for (int r = 1; r < 16; ++r) tmax = fmaxf(tmax, s[r]);
      tmax = fmaxf(tmax, __shfl_xor(tmax, 32, 64));

      if (!__all(tmax <= m + 8.0f)) {   // defer-max (T13)
        float mnew = fmaxf(m, tmax);
        float corr = exp2f(m - mnew);
        l *= corr;
#pragma unroll
        for (int dt = 0; dt < 4; ++dt)
#pragma unroll
          for (int r = 0; r < 16; ++r) acc[dt][r] *= corr;
        m = mnew;
      }

      float p[16];
      float ps = 0.f;
#pragma unroll
      for (int r = 0; r < 16; ++r) {
        p[r] = exp2f(s[r] - m);
        ps += p[r];
      }
      ps += __shfl_xor(ps, 32, 64);
      l += ps;

      unsigned int wk[8];
#pragma unroll
      for (int r = 0; r < 8; ++r) wk[r] = cvt_pk_bf16(p[2 * r], p[2 * r + 1]);

      __builtin_amdgcn_s_setprio(1);
#pragma unroll
      for (int kc = 0; kc < 2; ++kc) {
        unsigned int s0 = hi ? wk[4 * kc] : wk[4 * kc + 2];
        unsigned int s1 = hi ? wk[4 * kc + 1] : wk[4 * kc + 3];
        unsigned int z0 = (unsigned int)__shfl_xor((int)s0, 32, 64);
        unsigned int z1 = (unsigned int)__shfl_xor((int)s1, 32, 64);
        union { unsigned int u[4]; bf16w8 v; } pf;
        pf.u[0] = hi ? z0 : wk[4 * kc];
        pf.u[1] = hi ? z1 : wk[4 * kc + 1];
        pf.u[2] = hi ? wk[4 * kc + 2] : z0;
        pf.u[3] = hi ? wk[4 * kc + 3] : z1;
#pragma unroll
        for (int dt = 0; dt < 4; ++dt)
          acc[dt] = __builtin_amdgcn_mfma_f32_32x32x16_bf16(
              vf[dt * 2 + kc], pf.v, acc[dt], 0, 0, 0);
      }
      __builtin_amdgcn_s_setprio(0);
    }

    // ---- split-K combine: pairwise tree through LDS ----
    if (w == 1 || w == 3) {
      int slot = w >> 1;
#pragma unroll
      for (int dt = 0; dt < 4; ++dt)
#pragma unroll
        for (int r = 0; r < 16; ++r) cmb[slot][lane][dt * 16 + r] = acc[dt][r];
      cmb[slot][lane][64] = m;
      cmb[slot][lane][65] = l;
    }
    __syncthreads();
    if (w == 0 || w == 2) {
      int slot = w >> 1;
      float mo = cmb[slot][lane][64];
      float lo = cmb[slot][lane][65];
      float mf = fmaxf(m, mo);
      if (mf != -INFINITY) {
        float a = exp2f(m - mf);
        float bsc = exp2f(mo - mf);
        l = l * a + lo * bsc;
#pragma unroll
        for (int dt = 0; dt < 4; ++dt)
#pragma unroll
          for (int r = 0; r < 16; ++r)
            acc[dt][r] = acc[dt][r] * a + cmb[slot][lane][dt * 16 + r] * bsc;
        m = mf;
      }
    }
    __syncthreads();
    if (w == 2) {
#pragma unroll
      for (int dt = 0; dt < 4; ++dt)
#pragma unroll
        for (int r = 0; r < 16; ++r) cmb[1][lane][dt * 16 + r] = acc[dt][r];
      cmb[1][lane][64] = m;
      cmb[1][lane][65] = l;
    }
    __syncthreads();
    if (w == 0) {
      float mo = cmb[1][lane][64];
      float lo = cmb[1][lane][65];
      float mf = fmaxf(m, mo);
      float a = exp2f(m - mf);
      float bsc = exp2f(mo - mf);
      l = l * a + lo * bsc;
#pragma unroll
      for (int dt = 0; dt < 4; ++dt)
#pragma unroll
        for (int r = 0; r < 16; ++r)
          acc[dt][r] = acc[dt][r] * a + cmb[1][lane][dt * 16 + r] * bsc;

      float inv = 1.0f / l;
      // O^T: lane q = q31 fixed; d = dt*32 + 8*(r>>2) + 4*hi + (r&3)
      unsigned short* orow =
          Ob + ((size_t)(b * T_SEQ + q0 + q31)) * C_DIM + h * HD + hi * 4;
#pragma unroll
      for (int dt = 0; dt < 4; ++dt)
#pragma unroll
        for (int rq = 0; rq < 4; ++rq) {
          unsigned int w0 = cvt_pk_bf16(acc[dt][rq * 4 + 0] * inv,
                                        acc[dt][rq * 4 + 1] * inv);
          unsigned int w1 = cvt_pk_bf16(acc[dt][rq * 4 + 2] * inv,
                                        acc[dt][rq * 4 + 3] * inv);
          uint2 st; st.x = w0; st.y = w1;
          *(uint2*)(orow + dt * 32 + rq * 8) = st;
        }
    }
    __syncthreads();  // cmb safe to reuse for next side
  }
}

// ---------------------------------------------------------------------------
// Launch
// ---------------------------------------------------------------------------
extern "C" void kernel_launch(void* const* d_in, const int* in_sizes, int n_in,
                              void* d_out, int out_size, void* d_ws, size_t ws_size,
                              hipStream_t stream) {
  const float* x  = (const float*)d_in[0];
  const float* wq = (const float*)d_in[1];
  const float* wk = (const float*)d_in[2];
  const float* wv = (const float*)d_in[3];
  const float* wo = (const float*)d_in[4];
  const float* qw = (const float*)d_in[5];
  const float* kw = (const float*)d_in[6];
  float* out = (float*)d_out;

  char* p = (char*)d_ws;
  auto alloc = [&](size_t bytes) { void* r = (void*)p; p += (bytes + 255) & ~(size_t)255; return r; };
  float* qp   = (float*)alloc((size_t)M_ROWS * C_DIM * 4);
  float* kvp  = (float*)alloc((size_t)M_ROWS * 2 * KV_DIM * 4);  // K | V fused
  float* cost = (float*)alloc((size_t)T_SEQ * 64 * 4);
  float* sint = (float*)alloc((size_t)T_SEQ * 64 * 4);
  unsigned short* xb   = (unsigned short*)alloc((size_t)M_ROWS * C_DIM * 2);
  unsigned short* wqb  = (unsigned short*)alloc((size_t)C_DIM * C_DIM * 2);
  unsigned short* wkvb = (unsigned short*)alloc((size_t)2 * KV_DIM * C_DIM * 2);
  unsigned short* wob  = (unsigned short*)alloc((size_t)C_DIM * C_DIM * 2);
  unsigned short* qb   = (unsigned short*)alloc((size_t)M_ROWS * C_DIM * 2);
  unsigned short* kb   = (unsigned short*)alloc((size_t)M_ROWS * KV_DIM * 2);
  unsigned short* vt   = (unsigned short*)alloc((size_t)M_ROWS * KV_DIM * 2);
  unsigned short* attb = (unsigned short*)alloc((size_t)M_ROWS * C_DIM * 2);

  dim3 blk(256);
  rope_tables<<<dim3(T_SEQ), dim3(64), 0, stream>>>(cost, sint);

  // bf16 conversions (wk|wv concatenated -> fused KV weight [1024][2048])
  cvt_f32_bf16<<<dim3(M_ROWS * C_DIM / 2048), blk, 0, stream>>>(x, xb, M_ROWS * C_DIM / 8);
  cvt_f32_bf16<<<dim3(C_DIM * C_DIM / 2048), blk, 0, stream>>>(wq, wqb, C_DIM * C_DIM / 8);
  cvt_f32_bf16<<<dim3(KV_DIM * C_DIM / 2048), blk, 0, stream>>>(wk, wkvb, KV_DIM * C_DIM / 8);
  cvt_f32_bf16<<<dim3(KV_DIM * C_DIM / 2048), blk, 0, stream>>>(
      wv, wkvb + (size_t)KV_DIM * C_DIM, KV_DIM * C_DIM / 8);
  cvt_f32_bf16<<<dim3(C_DIM * C_DIM / 2048), blk, 0, stream>>>(wo, wob, C_DIM * C_DIM / 8);

  // Projections (m97-structure bf16 MFMA, fp32 out)
  gemm_lds_bf16<<<dim3(C_DIM / 128, M_ROWS / 128), blk, 0, stream>>>(
      xb, wqb, qp, M_ROWS, C_DIM, C_DIM);
  gemm_lds_bf16<<<dim3(2 * KV_DIM / 128, M_ROWS / 128), blk, 0, stream>>>(
      xb, wkvb, kvp, M_ROWS, 2 * KV_DIM, C_DIM);

  // RMSNorm + RoPE -> bf16. Q scale folds 1/sqrt(HD) AND log2(e) (exp2 domain).
  const float qscale = 0.08838834764831845f * 1.4426950408889634f;
  norm_rope_bf16<<<dim3(M_ROWS * NH / 4), blk, 0, stream>>>(
      qp, qb, qw, cost, sint, NH, C_DIM, C_DIM, qscale);
  norm_rope_bf16<<<dim3(M_ROWS * NKV / 4), blk, 0, stream>>>(
      kvp, kb, kw, cost, sint, NKV, 2 * KV_DIM, KV_DIM, 1.0f);

  // V (second half of fused KV) -> transposed bf16 (V^T)
  transpose_v<<<dim3(M_ROWS / 64, KV_DIM / 64), blk, 0, stream>>>(
      kvp + KV_DIM, vt, 2 * KV_DIM);

  // Flash attention v5: split-K, 1024 blocks x 4 waves, mirror-paired
  attn_mfma4<<<dim3(1024), blk, 0, stream>>>(qb, kb, vt, attb);

  // Output projection
  gemm_lds_bf16<<<dim3(C_DIM / 128, M_ROWS / 128), blk, 0, stream>>>(
      attb, wob, out, M_ROWS, C_DIM, C_DIM);
}

// Round 7
// 275.960 us; speedup vs baseline: 1.5430x; 1.5430x over previous
//
#include <hip/hip_runtime.h>
#include <math.h>

// Problem constants (B=2, T=2048, C=2048, 16 heads, 4 KV heads, HD=128)
#define NB 2
#define T_SEQ 2048
#define C_DIM 2048
#define NH 16
#define NKV 4
#define HD 128
#define KV_DIM (NKV * HD)   // 512
#define M_ROWS (NB * T_SEQ) // 4096
#define KTILE 8192          // elems per 64-key tile (64x128 K, 128x64 V^T)

typedef short bf16w8 __attribute__((ext_vector_type(8)));   // MFMA A/B frag (8 bf16)
typedef float f32x4 __attribute__((ext_vector_type(4)));    // 16x16 C/D frag
typedef float f32x16 __attribute__((ext_vector_type(16)));  // 32x32 C/D frag
typedef unsigned short u16x8 __attribute__((ext_vector_type(8)));
typedef unsigned short u16x4 __attribute__((ext_vector_type(4)));

#define AS1 __attribute__((address_space(1)))
#define AS3 __attribute__((address_space(3)))

__device__ __forceinline__ unsigned short f2bf(float x) {
  union { float f; unsigned u; } v; v.f = x;
  return (unsigned short)((v.u + 0x7FFFu + ((v.u >> 16) & 1u)) >> 16);
}

// packed bf16 pair: low = lo, high = hi
__device__ __forceinline__ unsigned int cvt_pk_bf16(float lo, float hi) {
  unsigned int r;
  asm("v_cvt_pk_bf16_f32 %0, %1, %2" : "=v"(r) : "v"(lo), "v"(hi));
  return r;
}

__device__ __forceinline__ float wave_reduce_sum(float v) {
#pragma unroll
  for (int off = 32; off > 0; off >>= 1) v += __shfl_xor(v, off, 64);
  return v;
}

// ---------------------------------------------------------------------------
// fp32 -> bf16 bulk convert (16B stores).
// ---------------------------------------------------------------------------
__global__ __launch_bounds__(256) void cvt_f32_bf16(
    const float* __restrict__ in, unsigned short* __restrict__ out, int n8) {
  int i = blockIdx.x * 256 + threadIdx.x;
  if (i >= n8) return;
  float4 a = ((const float4*)in)[i * 2];
  float4 b = ((const float4*)in)[i * 2 + 1];
  u16x8 o;
  o[0] = f2bf(a.x); o[1] = f2bf(a.y); o[2] = f2bf(a.z); o[3] = f2bf(a.w);
  o[4] = f2bf(b.x); o[5] = f2bf(b.y); o[6] = f2bf(b.z); o[7] = f2bf(b.w);
  *(u16x8*)(out + (size_t)i * 8) = o;
}

// ---------------------------------------------------------------------------
// RoPE cos/sin tables: [T][64] each. theta = 500000.
// ---------------------------------------------------------------------------
__global__ void rope_tables(float* __restrict__ cost, float* __restrict__ sint) {
  int t = blockIdx.x;
  int i = threadIdx.x; // 0..63
  float inv_freq = powf(500000.0f, -(float)i / 64.0f);
  float ang = (float)t * inv_freq;
  cost[t * 64 + i] = cosf(ang);
  sint[t * 64 + i] = sinf(ang);
}

// ---------------------------------------------------------------------------
// GEMM (m97 structure): C[M][N] = A[M][K] * W[N][K]^T, A/W bf16, C fp32.
// ---------------------------------------------------------------------------
__global__ __launch_bounds__(256) void gemm_lds_bf16(
    const unsigned short* __restrict__ A, const unsigned short* __restrict__ W,
    float* __restrict__ C, int M, int N, int K) {
  __shared__ __align__(16) unsigned short As[128 * 64];
  __shared__ __align__(16) unsigned short Ws[128 * 64];
  int tid = threadIdx.x;
  int lane = tid & 63;
  int w = tid >> 6;
  int wr = w >> 1, wc = w & 1;
  int l15 = lane & 15, l4 = lane >> 4;

  int segrow = lane >> 3;
  int segk = (lane & 7) * 8;
  const unsigned short* Ag =
      A + (size_t)(blockIdx.y * 128 + w * 32 + segrow) * K + segk;
  const unsigned short* Wg =
      W + (size_t)(blockIdx.x * 128 + w * 32 + segrow) * K + segk;

  f32x4 zero = {0.f, 0.f, 0.f, 0.f};
  f32x4 acc[4][4];
#pragma unroll
  for (int m = 0; m < 4; ++m)
#pragma unroll
    for (int n = 0; n < 4; ++n) acc[m][n] = zero;

  for (int k0 = 0; k0 < K; k0 += 64) {
    __syncthreads();
#pragma unroll
    for (int i = 0; i < 4; ++i) {
      __builtin_amdgcn_global_load_lds(
          (const AS1 void*)(Ag + k0 + (size_t)i * 8 * K),
          (AS3 void*)&As[(w * 32 + i * 8) * 64], 16, 0, 0);
      __builtin_amdgcn_global_load_lds(
          (const AS1 void*)(Wg + k0 + (size_t)i * 8 * K),
          (AS3 void*)&Ws[(w * 32 + i * 8) * 64], 16, 0, 0);
    }
    __syncthreads();

    bf16w8 af[2][4], bw[2][4];
#pragma unroll
    for (int kk = 0; kk < 2; ++kk) {
#pragma unroll
      for (int m = 0; m < 4; ++m)
        af[kk][m] = *(const bf16w8*)&As[(wr * 64 + m * 16 + l15) * 64 + kk * 32 + l4 * 8];
#pragma unroll
      for (int n = 0; n < 4; ++n)
        bw[kk][n] = *(const bf16w8*)&Ws[(wc * 64 + n * 16 + l15) * 64 + kk * 32 + l4 * 8];
    }
#pragma unroll
    for (int kk = 0; kk < 2; ++kk)
#pragma unroll
      for (int m = 0; m < 4; ++m)
#pragma unroll
        for (int n = 0; n < 4; ++n)
          acc[m][n] = __builtin_amdgcn_mfma_f32_16x16x32_bf16(
              af[kk][m], bw[kk][n], acc[m][n], 0, 0, 0);
  }

#pragma unroll
  for (int m = 0; m < 4; ++m)
#pragma unroll
    for (int n = 0; n < 4; ++n)
#pragma unroll
      for (int j = 0; j < 4; ++j) {
        int row = blockIdx.y * 128 + wr * 64 + m * 16 + l4 * 4 + j;
        int col = blockIdx.x * 128 + wc * 64 + n * 16 + l15;
        C[(size_t)row * N + col] = acc[m][n][j];
      }
}

// ---------------------------------------------------------------------------
// Per-head RMSNorm + RoPE, fp32 in -> bf16 out, row-major (used for Q).
// ---------------------------------------------------------------------------
__global__ __launch_bounds__(256) void norm_rope_bf16(
    const float* __restrict__ X, unsigned short* __restrict__ Y,
    const float* __restrict__ w, const float* __restrict__ cost,
    const float* __restrict__ sint, int nheads, int istride, int ostride,
    float oscale) {
  int wid = (blockIdx.x * 256 + threadIdx.x) >> 6;
  int lane = threadIdx.x & 63;
  int h = wid % nheads;
  int bt = wid / nheads;
  int t = bt & (T_SEQ - 1);
  const float* row = X + (size_t)bt * istride + h * HD;
  float x1 = row[lane];
  float x2 = row[lane + 64];
  float ss = wave_reduce_sum(x1 * x1 + x2 * x2);
  float r = rsqrtf(ss * (1.0f / 128.0f) + 1e-6f);
  x1 = x1 * r * w[lane];
  x2 = x2 * r * w[lane + 64];
  float c = cost[t * 64 + lane];
  float s = sint[t * 64 + lane];
  unsigned short* yrow = Y + (size_t)bt * ostride + h * HD;
  yrow[lane]      = f2bf((x1 * c - x2 * s) * oscale);
  yrow[lane + 64] = f2bf((x2 * c + x1 * s) * oscale);
}

// ---------------------------------------------------------------------------
// K RMSNorm + RoPE -> TILED bf16: Kt[(b*4+kvh)][kb][64 rows][128 cols],
// tile = 8192 elems contiguous. One wave per (bt, kvh).
// ---------------------------------------------------------------------------
__global__ __launch_bounds__(256) void norm_rope_k_tiled(
    const float* __restrict__ X, unsigned short* __restrict__ Y,
    const float* __restrict__ w, const float* __restrict__ cost,
    const float* __restrict__ sint) {
  int wid = (blockIdx.x * 256 + threadIdx.x) >> 6;
  int lane = threadIdx.x & 63;
  int kvh = wid & 3;
  int bt = wid >> 2;
  int t = bt & (T_SEQ - 1);
  int b = bt >> 11;
  const float* row = X + (size_t)bt * (2 * KV_DIM) + kvh * HD;
  float x1 = row[lane];
  float x2 = row[lane + 64];
  float ss = wave_reduce_sum(x1 * x1 + x2 * x2);
  float r = rsqrtf(ss * (1.0f / 128.0f) + 1e-6f);
  x1 = x1 * r * w[lane];
  x2 = x2 * r * w[lane + 64];
  float c = cost[t * 64 + lane];
  float s = sint[t * 64 + lane];
  size_t obase = ((size_t)((b * NKV + kvh) * 32 + (t >> 6))) * KTILE +
                 (size_t)(t & 63) * 128;
  Y[obase + lane]      = f2bf(x1 * c - x2 * s);
  Y[obase + lane + 64] = f2bf(x2 * c + x1 * s);
}

// ---------------------------------------------------------------------------
// V transpose -> TILED bf16 V^T: Vt[(b*4+kvh)][kb][128 rows=d][64 cols=keys].
// ---------------------------------------------------------------------------
__global__ __launch_bounds__(256) void transpose_v(
    const float* __restrict__ Vp, unsigned short* __restrict__ Vt, int istride) {
  __shared__ float tile[64][65];
  int bt_tile = blockIdx.x;           // 0..63  (b*32 + ttile)
  int ct = blockIdx.y;                // 0..7
  int b = bt_tile >> 5;
  int t0 = (bt_tile & 31) * 64;
  int c0 = ct * 64;
  int tid = threadIdx.x;
  int r = tid >> 4;                   // 0..15
  int c4 = (tid & 15) * 4;
#pragma unroll
  for (int p = 0; p < 4; ++p) {
    int row = r + p * 16;
    float4 v = *(const float4*)&Vp[(size_t)(b * T_SEQ + t0 + row) * istride + c0 + c4];
    tile[row][c4] = v.x; tile[row][c4 + 1] = v.y;
    tile[row][c4 + 2] = v.z; tile[row][c4 + 3] = v.w;
  }
  __syncthreads();
#pragma unroll
  for (int p = 0; p < 4; ++p) {
    int drow = r + p * 16;            // local col index = output row
    int cg = c0 + drow;               // 0..511
    int kvh2 = cg >> 7, dl = cg & 127;
    u16x4 o;
    o[0] = f2bf(tile[c4 + 0][drow]);
    o[1] = f2bf(tile[c4 + 1][drow]);
    o[2] = f2bf(tile[c4 + 2][drow]);
    o[3] = f2bf(tile[c4 + 3][drow]);
    size_t off = ((size_t)((b * NKV + kvh2) * 32 + (t0 >> 6))) * KTILE +
                 (size_t)dl * 64 + c4;
    *(u16x4*)&Vt[off] = o;
  }
}

// ---------------------------------------------------------------------------
// Causal GQA flash attention v6: LDS-staged K/V tiles (64 keys), coalesced
// global_load_lds staging with inverse-swizzled source (rule #21), XOR-
// swizzled ds_read_b128 fragments (granule ^= row&7, m214 recipe).
// Block = 4 waves = 4x32 q-rows of ONE head's 128-row chunk; processes
// chunk c then 15-c sequentially (uniform 34 staged iters/block).
// 256 blocks (1/CU); bid&7 = (b,kvh) -> one KV set per XCD L2.
// Per-wave math identical to verified round-4 body (swapped-operand QK,
// in-register softmax, defer-max, exp2, cvt_pk+shfl P^T exchange).
// ---------------------------------------------------------------------------
__global__ __launch_bounds__(256) void attn_mfma5(
    const unsigned short* __restrict__ Qb, const unsigned short* __restrict__ Kt,
    const unsigned short* __restrict__ Vt, unsigned short* __restrict__ Ob) {
  __shared__ __align__(16) unsigned short lds[2][16384];  // [buf][K 8192 | V 8192]
  int tid = threadIdx.x;
  int lane = tid & 63;
  int q31 = lane & 31;
  int hi = lane >> 5;
  int w = tid >> 6;
  int sw = q31 & 7;

  int bid = blockIdx.x;
  int grp = bid & 7;                  // (b,kvh) -> XCD
  int b = grp >> 2, kvh = grp & 3;
  int inner = bid >> 3;               // 0..31
  int h = kvh * 4 + (inner & 3);
  int cp = inner >> 2;                // 0..7

  const unsigned short* ktb = Kt + (size_t)(b * NKV + kvh) * 32 * KTILE;
  const unsigned short* vtb = Vt + (size_t)(b * NKV + kvh) * 32 * KTILE;

  for (int side = 0; side < 2; ++side) {
    int c = side ? (15 - cp) : cp;
    int q0 = c * 128 + w * 32;
    int nkb = 2 * c + 2;
    int my_kend = (q0 + 31) >> 6;

    const unsigned short* qptr =
        Qb + ((size_t)(b * T_SEQ + q0 + q31)) * C_DIM + h * HD + hi * 8;
    bf16w8 qf[8];
#pragma unroll
    for (int kc = 0; kc < 8; ++kc) qf[kc] = *(const bf16w8*)(qptr + kc * 16);

    f32x16 acc[4];
#pragma unroll
    for (int dt = 0; dt < 4; ++dt)
#pragma unroll
      for (int r = 0; r < 16; ++r) acc[dt][r] = 0.f;
    float m = -INFINITY, l = 0.f;

    // prologue: stage kb=0 -> buf 0
    {
      const unsigned short* kg_ = ktb;
      const unsigned short* vg_ = vtb;
#pragma unroll
      for (int i = 0; i < 4; ++i) {
        int s = i * 256 + w * 64 + lane;
        int rK = s >> 4; int gK = (s & 15) ^ (rK & 7);
        __builtin_amdgcn_global_load_lds(
            (const AS1 void*)(kg_ + rK * 128 + gK * 8),
            (AS3 void*)&lds[0][(i * 256 + w * 64) * 8], 16, 0, 0);
        int rV = s >> 3; int gV = (s & 7) ^ (rV & 7);
        __builtin_amdgcn_global_load_lds(
            (const AS1 void*)(vg_ + rV * 64 + gV * 8),
            (AS3 void*)&lds[0][8192 + (i * 256 + w * 64) * 8], 16, 0, 0);
      }
    }
    __syncthreads();

    for (int kb = 0; kb < nkb; ++kb) {
      int cur = kb & 1;
      if (kb + 1 < nkb) {  // stage next tile into other buffer
        const unsigned short* kg_ = ktb + (size_t)(kb + 1) * KTILE;
        const unsigned short* vg_ = vtb + (size_t)(kb + 1) * KTILE;
        unsigned short* dst = &lds[cur ^ 1][0];
#pragma unroll
        for (int i = 0; i < 4; ++i) {
          int s = i * 256 + w * 64 + lane;
          int rK = s >> 4; int gK = (s & 15) ^ (rK & 7);
          __builtin_amdgcn_global_load_lds(
              (const AS1 void*)(kg_ + rK * 128 + gK * 8),
              (AS3 void*)(dst + (i * 256 + w * 64) * 8), 16, 0, 0);
          int rV = s >> 3; int gV = (s & 7) ^ (rV & 7);
          __builtin_amdgcn_global_load_lds(
              (const AS1 void*)(vg_ + rV * 64 + gV * 8),
              (AS3 void*)(dst + 8192 + (i * 256 + w * 64) * 8), 16, 0, 0);
        }
      }

      if (kb <= my_kend) {
        const unsigned short* kbuf = &lds[cur][0];
        const unsigned short* vbuf = &lds[cur][8192];

        // --- QK^T for 64 keys: two 32-key groups ---
        f32x16 sA, sB;
#pragma unroll
        for (int r = 0; r < 16; ++r) { sA[r] = 0.f; sB[r] = 0.f; }
        {
          bf16w8 kf[8];
#pragma unroll
          for (int kc = 0; kc < 8; ++kc)
            kf[kc] = *(const bf16w8*)&kbuf[q31 * 128 + (((kc * 2 + hi) ^ sw) * 8)];
          __builtin_amdgcn_s_setprio(1);
#pragma unroll
          for (int kc = 0; kc < 8; ++kc)
            sA = __builtin_amdgcn_mfma_f32_32x32x16_bf16(kf[kc], qf[kc], sA, 0, 0, 0);
          __builtin_amdgcn_s_setprio(0);
        }
        {
          bf16w8 kf[8];
#pragma unroll
          for (int kc = 0; kc < 8; ++kc)
            kf[kc] = *(const bf16w8*)&kbuf[(32 + q31) * 128 + (((kc * 2 + hi) ^ sw) * 8)];
          __builtin_amdgcn_s_setprio(1);
#pragma unroll
          for (int kc = 0; kc < 8; ++kc)
            sB = __builtin_amdgcn_mfma_f32_32x32x16_bf16(kf[kc], qf[kc], sB, 0, 0, 0);
          __builtin_amdgcn_s_setprio(0);
        }

        if (kb == my_kend) {  // diagonal: mask key > q
#pragma unroll
          for (int r = 0; r < 16; ++r) {
            int keyl = (r & 3) + 8 * (r >> 2) + 4 * hi;
            if (kb * 64 + keyl > q0 + q31) sA[r] = -INFINITY;
            if (kb * 64 + 32 + keyl > q0 + q31) sB[r] = -INFINITY;
          }
        }

        float tmax = sA[0];
#pragma unroll
        for (int r = 1; r < 16; ++r) tmax = fmaxf(tmax, sA[r]);
#pragma unroll
        for (int r = 0; r < 16; ++r) tmax = fmaxf(tmax, sB[r]);
        tmax = fmaxf(tmax, __shfl_xor(tmax, 32, 64));

        if (!__all(tmax <= m + 8.0f)) {   // defer-max (T13)
          float mnew = fmaxf(m, tmax);
          float corr = exp2f(m - mnew);
          l *= corr;
#pragma unroll
          for (int dt = 0; dt < 4; ++dt)
#pragma unroll
            for (int r = 0; r < 16; ++r) acc[dt][r] *= corr;
          m = mnew;
        }

        float pA[16], pB[16];
        float ps = 0.f;
#pragma unroll
        for (int r = 0; r < 16; ++r) {
          pA[r] = exp2f(sA[r] - m);
          pB[r] = exp2f(sB[r] - m);
          ps += pA[r] + pB[r];
        }
        ps += __shfl_xor(ps, 32, 64);
        l += ps;

        unsigned int wkA[8], wkB[8];
#pragma unroll
        for (int r = 0; r < 8; ++r) {
          wkA[r] = cvt_pk_bf16(pA[2 * r], pA[2 * r + 1]);
          wkB[r] = cvt_pk_bf16(pB[2 * r], pB[2 * r + 1]);
        }

        // --- PV: 4 key-chunks of 16 (kg0: kc4=0,1; kg1: kc4=2,3) ---
        __builtin_amdgcn_s_setprio(1);
#pragma unroll
        for (int kg = 0; kg < 2; ++kg) {
#pragma unroll
          for (int kc = 0; kc < 2; ++kc) {
            int kc4 = kg * 2 + kc;
            unsigned int* wk = kg ? wkB : wkA;
            unsigned int s0 = hi ? wk[4 * kc] : wk[4 * kc + 2];
            unsigned int s1 = hi ? wk[4 * kc + 1] : wk[4 * kc + 3];
            unsigned int z0 = (unsigned int)__shfl_xor((int)s0, 32, 64);
            unsigned int z1 = (unsigned int)__shfl_xor((int)s1, 32, 64);
            union { unsigned int u[4]; bf16w8 v; } pf;
            pf.u[0] = hi ? z0 : wk[4 * kc];
            pf.u[1] = hi ? z1 : wk[4 * kc + 1];
            pf.u[2] = hi ? wk[4 * kc + 2] : z0;
            pf.u[3] = hi ? wk[4 * kc + 3] : z1;
#pragma unroll
            for (int dt = 0; dt < 4; ++dt) {
              bf16w8 vf = *(const bf16w8*)&vbuf[(dt * 32 + q31) * 64 +
                                                (((kc4 * 2 + hi) ^ sw) * 8)];
              acc[dt] = __builtin_amdgcn_mfma_f32_32x32x16_bf16(
                  vf, pf.v, acc[dt], 0, 0, 0);
            }
          }
        }
        __builtin_amdgcn_s_setprio(0);
      }
      __syncthreads();  // next buf staged; all reads of cur done
    }

    float inv = 1.0f / l;
    // O^T: lane q = q31 fixed; d = dt*32 + 8*(r>>2) + 4*hi + (r&3)
    unsigned short* orow =
        Ob + ((size_t)(b * T_SEQ + q0 + q31)) * C_DIM + h * HD + hi * 4;
#pragma unroll
    for (int dt = 0; dt < 4; ++dt)
#pragma unroll
      for (int rq = 0; rq < 4; ++rq) {
        unsigned int w0 = cvt_pk_bf16(acc[dt][rq * 4 + 0] * inv,
                                      acc[dt][rq * 4 + 1] * inv);
        unsigned int w1 = cvt_pk_bf16(acc[dt][rq * 4 + 2] * inv,
                                      acc[dt][rq * 4 + 3] * inv);
        uint2 st; st.x = w0; st.y = w1;
        *(uint2*)(orow + dt * 32 + rq * 8) = st;
      }
  }
}

// ---------------------------------------------------------------------------
// Launch
// ---------------------------------------------------------------------------
extern "C" void kernel_launch(void* const* d_in, const int* in_sizes, int n_in,
                              void* d_out, int out_size, void* d_ws, size_t ws_size,
                              hipStream_t stream) {
  const float* x  = (const float*)d_in[0];
  const float* wq = (const float*)d_in[1];
  const float* wk = (const float*)d_in[2];
  const float* wv = (const float*)d_in[3];
  const float* wo = (const float*)d_in[4];
  const float* qw = (const float*)d_in[5];
  const float* kw = (const float*)d_in[6];
  float* out = (float*)d_out;

  char* p = (char*)d_ws;
  auto alloc = [&](size_t bytes) { void* r = (void*)p; p += (bytes + 255) & ~(size_t)255; return r; };
  float* qp   = (float*)alloc((size_t)M_ROWS * C_DIM * 4);
  float* kvp  = (float*)alloc((size_t)M_ROWS * 2 * KV_DIM * 4);  // K | V fused
  float* cost = (float*)alloc((size_t)T_SEQ * 64 * 4);
  float* sint = (float*)alloc((size_t)T_SEQ * 64 * 4);
  unsigned short* xb   = (unsigned short*)alloc((size_t)M_ROWS * C_DIM * 2);
  unsigned short* wqb  = (unsigned short*)alloc((size_t)C_DIM * C_DIM * 2);
  unsigned short* wkvb = (unsigned short*)alloc((size_t)2 * KV_DIM * C_DIM * 2);
  unsigned short* wob  = (unsigned short*)alloc((size_t)C_DIM * C_DIM * 2);
  unsigned short* qb   = (unsigned short*)alloc((size_t)M_ROWS * C_DIM * 2);
  unsigned short* ktil = (unsigned short*)alloc((size_t)NB * NKV * 32 * KTILE * 2);
  unsigned short* vtil = (unsigned short*)alloc((size_t)NB * NKV * 32 * KTILE * 2);
  unsigned short* attb = (unsigned short*)alloc((size_t)M_ROWS * C_DIM * 2);

  dim3 blk(256);
  rope_tables<<<dim3(T_SEQ), dim3(64), 0, stream>>>(cost, sint);

  // bf16 conversions (wk|wv concatenated -> fused KV weight [1024][2048])
  cvt_f32_bf16<<<dim3(M_ROWS * C_DIM / 2048), blk, 0, stream>>>(x, xb, M_ROWS * C_DIM / 8);
  cvt_f32_bf16<<<dim3(C_DIM * C_DIM / 2048), blk, 0, stream>>>(wq, wqb, C_DIM * C_DIM / 8);
  cvt_f32_bf16<<<dim3(KV_DIM * C_DIM / 2048), blk, 0, stream>>>(wk, wkvb, KV_DIM * C_DIM / 8);
  cvt_f32_bf16<<<dim3(KV_DIM * C_DIM / 2048), blk, 0, stream>>>(
      wv, wkvb + (size_t)KV_DIM * C_DIM, KV_DIM * C_DIM / 8);
  cvt_f32_bf16<<<dim3(C_DIM * C_DIM / 2048), blk, 0, stream>>>(wo, wob, C_DIM * C_DIM / 8);

  // Projections (m97-structure bf16 MFMA, fp32 out)
  gemm_lds_bf16<<<dim3(C_DIM / 128, M_ROWS / 128), blk, 0, stream>>>(
      xb, wqb, qp, M_ROWS, C_DIM, C_DIM);
  gemm_lds_bf16<<<dim3(2 * KV_DIM / 128, M_ROWS / 128), blk, 0, stream>>>(
      xb, wkvb, kvp, M_ROWS, 2 * KV_DIM, C_DIM);

  // RMSNorm + RoPE. Q: row-major bf16, scale folds 1/sqrt(HD) and log2(e).
  const float qscale = 0.08838834764831845f * 1.4426950408889634f;
  norm_rope_bf16<<<dim3(M_ROWS * NH / 4), blk, 0, stream>>>(
      qp, qb, qw, cost, sint, NH, C_DIM, C_DIM, qscale);
  // K: tiled layout for LDS staging
  norm_rope_k_tiled<<<dim3(M_ROWS * NKV / 4), blk, 0, stream>>>(
      kvp, ktil, kw, cost, sint);

  // V (second half of fused KV) -> tiled transposed bf16 (V^T)
  transpose_v<<<dim3(M_ROWS / 64, KV_DIM / 64), blk, 0, stream>>>(
      kvp + KV_DIM, vtil, 2 * KV_DIM);

  // Flash attention v6: 256 blocks x 4 waves, LDS-staged, mirror-paired
  attn_mfma5<<<dim3(256), blk, 0, stream>>>(qb, ktil, vtil, attb);

  // Output projection
  gemm_lds_bf16<<<dim3(C_DIM / 128, M_ROWS / 128), blk, 0, stream>>>(
      attb, wob, out, M_ROWS, C_DIM, C_DIM);
}

// Round 8
// 264.098 us; speedup vs baseline: 1.6123x; 1.0449x over previous
//
#include <hip/hip_runtime.h>
#include <math.h>

// Problem constants (B=2, T=2048, C=2048, 16 heads, 4 KV heads, HD=128)
#define NB 2
#define T_SEQ 2048
#define C_DIM 2048
#define NH 16
#define NKV 4
#define HD 128
#define KV_DIM (NKV * HD)   // 512
#define M_ROWS (NB * T_SEQ) // 4096
#define KTILE 8192          // elems per 64-key tile (64x128 K, 128x64 V^T)
#define QKV_N 3072          // fused Q|K|V projection width

typedef short bf16w8 __attribute__((ext_vector_type(8)));   // MFMA A/B frag (8 bf16)
typedef float f32x4 __attribute__((ext_vector_type(4)));    // 16x16 C/D frag
typedef float f32x16 __attribute__((ext_vector_type(16)));  // 32x32 C/D frag
typedef unsigned short u16x8 __attribute__((ext_vector_type(8)));
typedef unsigned short u16x4 __attribute__((ext_vector_type(4)));

#define AS1 __attribute__((address_space(1)))
#define AS3 __attribute__((address_space(3)))

__device__ __forceinline__ unsigned short f2bf(float x) {
  union { float f; unsigned u; } v; v.f = x;
  return (unsigned short)((v.u + 0x7FFFu + ((v.u >> 16) & 1u)) >> 16);
}

// packed bf16 pair: low = lo, high = hi
__device__ __forceinline__ unsigned int cvt_pk_bf16(float lo, float hi) {
  unsigned int r;
  asm("v_cvt_pk_bf16_f32 %0, %1, %2" : "=v"(r) : "v"(lo), "v"(hi));
  return r;
}

__device__ __forceinline__ float wave_reduce_sum(float v) {
#pragma unroll
  for (int off = 32; off > 0; off >>= 1) v += __shfl_xor(v, off, 64);
  return v;
}

// ---------------------------------------------------------------------------
// fp32 -> bf16 bulk convert (16B stores).
// ---------------------------------------------------------------------------
__global__ __launch_bounds__(256) void cvt_f32_bf16(
    const float* __restrict__ in, unsigned short* __restrict__ out, int n8) {
  int i = blockIdx.x * 256 + threadIdx.x;
  if (i >= n8) return;
  float4 a = ((const float4*)in)[i * 2];
  float4 b = ((const float4*)in)[i * 2 + 1];
  u16x8 o;
  o[0] = f2bf(a.x); o[1] = f2bf(a.y); o[2] = f2bf(a.z); o[3] = f2bf(a.w);
  o[4] = f2bf(b.x); o[5] = f2bf(b.y); o[6] = f2bf(b.z); o[7] = f2bf(b.w);
  *(u16x8*)(out + (size_t)i * 8) = o;
}

// ---------------------------------------------------------------------------
// RoPE cos/sin tables: [T][64] each. theta = 500000.
// ---------------------------------------------------------------------------
__global__ void rope_tables(float* __restrict__ cost, float* __restrict__ sint) {
  int t = blockIdx.x;
  int i = threadIdx.x; // 0..63
  float inv_freq = powf(500000.0f, -(float)i / 64.0f);
  float ang = (float)t * inv_freq;
  cost[t * 64 + i] = cosf(ang);
  sint[t * 64 + i] = sinf(ang);
}

// ---------------------------------------------------------------------------
// GEMM (m97 structure): C[M][N] = A[M][K] * W[N][K]^T, A/W bf16, C fp32.
// ---------------------------------------------------------------------------
__global__ __launch_bounds__(256) void gemm_lds_bf16(
    const unsigned short* __restrict__ A, const unsigned short* __restrict__ W,
    float* __restrict__ C, int M, int N, int K) {
  __shared__ __align__(16) unsigned short As[128 * 64];
  __shared__ __align__(16) unsigned short Ws[128 * 64];
  int tid = threadIdx.x;
  int lane = tid & 63;
  int w = tid >> 6;
  int wr = w >> 1, wc = w & 1;
  int l15 = lane & 15, l4 = lane >> 4;

  int segrow = lane >> 3;
  int segk = (lane & 7) * 8;
  const unsigned short* Ag =
      A + (size_t)(blockIdx.y * 128 + w * 32 + segrow) * K + segk;
  const unsigned short* Wg =
      W + (size_t)(blockIdx.x * 128 + w * 32 + segrow) * K + segk;

  f32x4 zero = {0.f, 0.f, 0.f, 0.f};
  f32x4 acc[4][4];
#pragma unroll
  for (int m = 0; m < 4; ++m)
#pragma unroll
    for (int n = 0; n < 4; ++n) acc[m][n] = zero;

  for (int k0 = 0; k0 < K; k0 += 64) {
    __syncthreads();
#pragma unroll
    for (int i = 0; i < 4; ++i) {
      __builtin_amdgcn_global_load_lds(
          (const AS1 void*)(Ag + k0 + (size_t)i * 8 * K),
          (AS3 void*)&As[(w * 32 + i * 8) * 64], 16, 0, 0);
      __builtin_amdgcn_global_load_lds(
          (const AS1 void*)(Wg + k0 + (size_t)i * 8 * K),
          (AS3 void*)&Ws[(w * 32 + i * 8) * 64], 16, 0, 0);
    }
    __syncthreads();

    bf16w8 af[2][4], bw[2][4];
#pragma unroll
    for (int kk = 0; kk < 2; ++kk) {
#pragma unroll
      for (int m = 0; m < 4; ++m)
        af[kk][m] = *(const bf16w8*)&As[(wr * 64 + m * 16 + l15) * 64 + kk * 32 + l4 * 8];
#pragma unroll
      for (int n = 0; n < 4; ++n)
        bw[kk][n] = *(const bf16w8*)&Ws[(wc * 64 + n * 16 + l15) * 64 + kk * 32 + l4 * 8];
    }
#pragma unroll
    for (int kk = 0; kk < 2; ++kk)
#pragma unroll
      for (int m = 0; m < 4; ++m)
#pragma unroll
        for (int n = 0; n < 4; ++n)
          acc[m][n] = __builtin_amdgcn_mfma_f32_16x16x32_bf16(
              af[kk][m], bw[kk][n], acc[m][n], 0, 0, 0);
  }

#pragma unroll
  for (int m = 0; m < 4; ++m)
#pragma unroll
    for (int n = 0; n < 4; ++n)
#pragma unroll
      for (int j = 0; j < 4; ++j) {
        int row = blockIdx.y * 128 + wr * 64 + m * 16 + l4 * 4 + j;
        int col = blockIdx.x * 128 + wc * 64 + n * 16 + l15;
        C[(size_t)row * N + col] = acc[m][n][j];
      }
}

// ---------------------------------------------------------------------------
// Per-head RMSNorm + RoPE, fp32 in -> bf16 out, row-major (used for Q).
// ---------------------------------------------------------------------------
__global__ __launch_bounds__(256) void norm_rope_bf16(
    const float* __restrict__ X, unsigned short* __restrict__ Y,
    const float* __restrict__ w, const float* __restrict__ cost,
    const float* __restrict__ sint, int nheads, int istride, int ostride,
    float oscale) {
  int wid = (blockIdx.x * 256 + threadIdx.x) >> 6;
  int lane = threadIdx.x & 63;
  int h = wid % nheads;
  int bt = wid / nheads;
  int t = bt & (T_SEQ - 1);
  const float* row = X + (size_t)bt * istride + h * HD;
  float x1 = row[lane];
  float x2 = row[lane + 64];
  float ss = wave_reduce_sum(x1 * x1 + x2 * x2);
  float r = rsqrtf(ss * (1.0f / 128.0f) + 1e-6f);
  x1 = x1 * r * w[lane];
  x2 = x2 * r * w[lane + 64];
  float c = cost[t * 64 + lane];
  float s = sint[t * 64 + lane];
  unsigned short* yrow = Y + (size_t)bt * ostride + h * HD;
  yrow[lane]      = f2bf((x1 * c - x2 * s) * oscale);
  yrow[lane + 64] = f2bf((x2 * c + x1 * s) * oscale);
}

// ---------------------------------------------------------------------------
// K RMSNorm + RoPE -> TILED bf16: Kt[(b*4+kvh)][kb][64 rows][128 cols].
// ---------------------------------------------------------------------------
__global__ __launch_bounds__(256) void norm_rope_k_tiled(
    const float* __restrict__ X, unsigned short* __restrict__ Y,
    const float* __restrict__ w, const float* __restrict__ cost,
    const float* __restrict__ sint, int istride) {
  int wid = (blockIdx.x * 256 + threadIdx.x) >> 6;
  int lane = threadIdx.x & 63;
  int kvh = wid & 3;
  int bt = wid >> 2;
  int t = bt & (T_SEQ - 1);
  int b = bt >> 11;
  const float* row = X + (size_t)bt * istride + kvh * HD;
  float x1 = row[lane];
  float x2 = row[lane + 64];
  float ss = wave_reduce_sum(x1 * x1 + x2 * x2);
  float r = rsqrtf(ss * (1.0f / 128.0f) + 1e-6f);
  x1 = x1 * r * w[lane];
  x2 = x2 * r * w[lane + 64];
  float c = cost[t * 64 + lane];
  float s = sint[t * 64 + lane];
  size_t obase = ((size_t)((b * NKV + kvh) * 32 + (t >> 6))) * KTILE +
                 (size_t)(t & 63) * 128;
  Y[obase + lane]      = f2bf(x1 * c - x2 * s);
  Y[obase + lane + 64] = f2bf(x2 * c + x1 * s);
}

// ---------------------------------------------------------------------------
// V transpose -> TILED bf16 V^T: Vt[(b*4+kvh)][kb][128 rows=d][64 cols=keys].
// ---------------------------------------------------------------------------
__global__ __launch_bounds__(256) void transpose_v(
    const float* __restrict__ Vp, unsigned short* __restrict__ Vt, int istride) {
  __shared__ float tile[64][65];
  int bt_tile = blockIdx.x;           // 0..63  (b*32 + ttile)
  int ct = blockIdx.y;                // 0..7
  int b = bt_tile >> 5;
  int t0 = (bt_tile & 31) * 64;
  int c0 = ct * 64;
  int tid = threadIdx.x;
  int r = tid >> 4;                   // 0..15
  int c4 = (tid & 15) * 4;
#pragma unroll
  for (int p = 0; p < 4; ++p) {
    int row = r + p * 16;
    float4 v = *(const float4*)&Vp[(size_t)(b * T_SEQ + t0 + row) * istride + c0 + c4];
    tile[row][c4] = v.x; tile[row][c4 + 1] = v.y;
    tile[row][c4 + 2] = v.z; tile[row][c4 + 3] = v.w;
  }
  __syncthreads();
#pragma unroll
  for (int p = 0; p < 4; ++p) {
    int drow = r + p * 16;            // local col index = output row
    int cg = c0 + drow;               // 0..511
    int kvh2 = cg >> 7, dl = cg & 127;
    u16x4 o;
    o[0] = f2bf(tile[c4 + 0][drow]);
    o[1] = f2bf(tile[c4 + 1][drow]);
    o[2] = f2bf(tile[c4 + 2][drow]);
    o[3] = f2bf(tile[c4 + 3][drow]);
    size_t off = ((size_t)((b * NKV + kvh2) * 32 + (t0 >> 6))) * KTILE +
                 (size_t)dl * 64 + c4;
    *(u16x4*)&Vt[off] = o;
  }
}

// ---------------------------------------------------------------------------
// Causal GQA flash attention v7: LDS-staged K/V tiles, 8 waves/block with
// BOTH mirror chunks concurrent (waves 0-3: chunk cp, waves 4-7: 15-cp),
// one shared staging stream -> 2048 resident waves (2/SIMD).
// Per-wave math identical to verified round-4/7 body.
// 256 blocks (1/CU); bid&7 = (b,kvh) -> one KV set per XCD L2.
// ---------------------------------------------------------------------------
__global__ __launch_bounds__(512) void attn_mfma6(
    const unsigned short* __restrict__ Qb, const unsigned short* __restrict__ Kt,
    const unsigned short* __restrict__ Vt, unsigned short* __restrict__ Ob) {
  __shared__ __align__(16) unsigned short lds[2][16384];  // [buf][K 8192 | V 8192]
  int tid = threadIdx.x;
  int lane = tid & 63;
  int q31 = lane & 31;
  int hi = lane >> 5;
  int w = tid >> 6;                   // 0..7
  int sub = w & 3;
  int side = w >> 2;
  int sw = q31 & 7;

  int bid = blockIdx.x;
  int grp = bid & 7;                  // (b,kvh) -> XCD
  int b = grp >> 2, kvh = grp & 3;
  int inner = bid >> 3;               // 0..31
  int h = kvh * 4 + (inner & 3);
  int cp = inner >> 2;                // 0..7

  int c = side ? (15 - cp) : cp;      // this wave's 128-row chunk
  int q0 = c * 128 + sub * 32;
  int my_kend = 2 * c + (sub >> 1);
  int nkb_s0 = 2 * cp + 2;
  int nkb_s1 = 32 - 2 * cp;
  int nkb = nkb_s0 > nkb_s1 ? nkb_s0 : nkb_s1;   // block staging count

  const unsigned short* ktb = Kt + (size_t)(b * NKV + kvh) * 32 * KTILE;
  const unsigned short* vtb = Vt + (size_t)(b * NKV + kvh) * 32 * KTILE;

  // Q fragments (B-operand): col=q=q31, k = kc*16 + hi*8 + j
  const unsigned short* qptr =
      Qb + ((size_t)(b * T_SEQ + q0 + q31)) * C_DIM + h * HD + hi * 8;
  bf16w8 qf[8];
#pragma unroll
  for (int kc = 0; kc < 8; ++kc) qf[kc] = *(const bf16w8*)(qptr + kc * 16);

  f32x16 acc[4];
#pragma unroll
  for (int dt = 0; dt < 4; ++dt)
#pragma unroll
    for (int r = 0; r < 16; ++r) acc[dt][r] = 0.f;
  float m = -INFINITY, l = 0.f;

  // prologue: stage kb=0 -> buf 0 (512 threads, 2 chunks of 16B each per array)
  {
#pragma unroll
    for (int i = 0; i < 2; ++i) {
      int s = i * 512 + w * 64 + lane;
      int rK = s >> 4; int gK = (s & 15) ^ (rK & 7);
      __builtin_amdgcn_global_load_lds(
          (const AS1 void*)(ktb + rK * 128 + gK * 8),
          (AS3 void*)&lds[0][s * 8], 16, 0, 0);
      int rV = s >> 3; int gV = (s & 7) ^ (rV & 7);
      __builtin_amdgcn_global_load_lds(
          (const AS1 void*)(vtb + rV * 64 + gV * 8),
          (AS3 void*)&lds[0][8192 + s * 8], 16, 0, 0);
    }
  }
  __syncthreads();

  for (int kb = 0; kb < nkb; ++kb) {
    int cur = kb & 1;
    if (kb + 1 < nkb) {  // stage next tile into other buffer
      const unsigned short* kg_ = ktb + (size_t)(kb + 1) * KTILE;
      const unsigned short* vg_ = vtb + (size_t)(kb + 1) * KTILE;
      unsigned short* dst = &lds[cur ^ 1][0];
#pragma unroll
      for (int i = 0; i < 2; ++i) {
        int s = i * 512 + w * 64 + lane;
        int rK = s >> 4; int gK = (s & 15) ^ (rK & 7);
        __builtin_amdgcn_global_load_lds(
            (const AS1 void*)(kg_ + rK * 128 + gK * 8),
            (AS3 void*)(dst + s * 8), 16, 0, 0);
        int rV = s >> 3; int gV = (s & 7) ^ (rV & 7);
        __builtin_amdgcn_global_load_lds(
            (const AS1 void*)(vg_ + rV * 64 + gV * 8),
            (AS3 void*)(dst + 8192 + s * 8), 16, 0, 0);
      }
    }

    if (kb <= my_kend) {
      const unsigned short* kbuf = &lds[cur][0];
      const unsigned short* vbuf = &lds[cur][8192];

      // --- QK^T for 64 keys: two 32-key groups ---
      f32x16 sA, sB;
#pragma unroll
      for (int r = 0; r < 16; ++r) { sA[r] = 0.f; sB[r] = 0.f; }
      {
        bf16w8 kf[8];
#pragma unroll
        for (int kc = 0; kc < 8; ++kc)
          kf[kc] = *(const bf16w8*)&kbuf[q31 * 128 + (((kc * 2 + hi) ^ sw) * 8)];
        __builtin_amdgcn_s_setprio(1);
#pragma unroll
        for (int kc = 0; kc < 8; ++kc)
          sA = __builtin_amdgcn_mfma_f32_32x32x16_bf16(kf[kc], qf[kc], sA, 0, 0, 0);
        __builtin_amdgcn_s_setprio(0);
      }
      {
        bf16w8 kf[8];
#pragma unroll
        for (int kc = 0; kc < 8; ++kc)
          kf[kc] = *(const bf16w8*)&kbuf[(32 + q31) * 128 + (((kc * 2 + hi) ^ sw) * 8)];
        __builtin_amdgcn_s_setprio(1);
#pragma unroll
        for (int kc = 0; kc < 8; ++kc)
          sB = __builtin_amdgcn_mfma_f32_32x32x16_bf16(kf[kc], qf[kc], sB, 0, 0, 0);
        __builtin_amdgcn_s_setprio(0);
      }

      if (kb == my_kend) {  // diagonal: mask key > q
#pragma unroll
        for (int r = 0; r < 16; ++r) {
          int keyl = (r & 3) + 8 * (r >> 2) + 4 * hi;
          if (kb * 64 + keyl > q0 + q31) sA[r] = -INFINITY;
          if (kb * 64 + 32 + keyl > q0 + q31) sB[r] = -INFINITY;
        }
      }

      float tmax = sA[0];
#pragma unroll
      for (int r = 1; r < 16; ++r) tmax = fmaxf(tmax, sA[r]);
#pragma unroll
      for (int r = 0; r < 16; ++r) tmax = fmaxf(tmax, sB[r]);
      tmax = fmaxf(tmax, __shfl_xor(tmax, 32, 64));

      if (!__all(tmax <= m + 8.0f)) {   // defer-max (T13)
        float mnew = fmaxf(m, tmax);
        float corr = exp2f(m - mnew);
        l *= corr;
#pragma unroll
        for (int dt = 0; dt < 4; ++dt)
#pragma unroll
          for (int r = 0; r < 16; ++r) acc[dt][r] *= corr;
        m = mnew;
      }

      float pA[16], pB[16];
      float ps = 0.f;
#pragma unroll
      for (int r = 0; r < 16; ++r) {
        pA[r] = exp2f(sA[r] - m);
        pB[r] = exp2f(sB[r] - m);
        ps += pA[r] + pB[r];
      }
      ps += __shfl_xor(ps, 32, 64);
      l += ps;

      unsigned int wkA[8], wkB[8];
#pragma unroll
      for (int r = 0; r < 8; ++r) {
        wkA[r] = cvt_pk_bf16(pA[2 * r], pA[2 * r + 1]);
        wkB[r] = cvt_pk_bf16(pB[2 * r], pB[2 * r + 1]);
      }

      // --- PV: 4 key-chunks of 16 ---
      __builtin_amdgcn_s_setprio(1);
#pragma unroll
      for (int kg = 0; kg < 2; ++kg) {
#pragma unroll
        for (int kc = 0; kc < 2; ++kc) {
          int kc4 = kg * 2 + kc;
          unsigned int* wk = kg ? wkB : wkA;
          unsigned int s0 = hi ? wk[4 * kc] : wk[4 * kc + 2];
          unsigned int s1 = hi ? wk[4 * kc + 1] : wk[4 * kc + 3];
          unsigned int z0 = (unsigned int)__shfl_xor((int)s0, 32, 64);
          unsigned int z1 = (unsigned int)__shfl_xor((int)s1, 32, 64);
          union { unsigned int u[4]; bf16w8 v; } pf;
          pf.u[0] = hi ? z0 : wk[4 * kc];
          pf.u[1] = hi ? z1 : wk[4 * kc + 1];
          pf.u[2] = hi ? wk[4 * kc + 2] : z0;
          pf.u[3] = hi ? wk[4 * kc + 3] : z1;
#pragma unroll
          for (int dt = 0; dt < 4; ++dt) {
            bf16w8 vf = *(const bf16w8*)&vbuf[(dt * 32 + q31) * 64 +
                                              (((kc4 * 2 + hi) ^ sw) * 8)];
            acc[dt] = __builtin_amdgcn_mfma_f32_32x32x16_bf16(
                vf, pf.v, acc[dt], 0, 0, 0);
          }
        }
      }
      __builtin_amdgcn_s_setprio(0);
    }
    __syncthreads();  // next buf staged; all reads of cur done
  }

  float inv = 1.0f / l;
  // O^T: lane q = q31 fixed; d = dt*32 + 8*(r>>2) + 4*hi + (r&3)
  unsigned short* orow =
      Ob + ((size_t)(b * T_SEQ + q0 + q31)) * C_DIM + h * HD + hi * 4;
#pragma unroll
  for (int dt = 0; dt < 4; ++dt)
#pragma unroll
    for (int rq = 0; rq < 4; ++rq) {
      unsigned int w0 = cvt_pk_bf16(acc[dt][rq * 4 + 0] * inv,
                                    acc[dt][rq * 4 + 1] * inv);
      unsigned int w1 = cvt_pk_bf16(acc[dt][rq * 4 + 2] * inv,
                                    acc[dt][rq * 4 + 3] * inv);
      uint2 st; st.x = w0; st.y = w1;
      *(uint2*)(orow + dt * 32 + rq * 8) = st;
    }
}

// ---------------------------------------------------------------------------
// Launch
// ---------------------------------------------------------------------------
extern "C" void kernel_launch(void* const* d_in, const int* in_sizes, int n_in,
                              void* d_out, int out_size, void* d_ws, size_t ws_size,
                              hipStream_t stream) {
  const float* x  = (const float*)d_in[0];
  const float* wq = (const float*)d_in[1];
  const float* wk = (const float*)d_in[2];
  const float* wv = (const float*)d_in[3];
  const float* wo = (const float*)d_in[4];
  const float* qw = (const float*)d_in[5];
  const float* kw = (const float*)d_in[6];
  float* out = (float*)d_out;

  char* p = (char*)d_ws;
  auto alloc = [&](size_t bytes) { void* r = (void*)p; p += (bytes + 255) & ~(size_t)255; return r; };
  float* qkvp = (float*)alloc((size_t)M_ROWS * QKV_N * 4);   // Q|K|V fused fp32
  float* cost = (float*)alloc((size_t)T_SEQ * 64 * 4);
  float* sint = (float*)alloc((size_t)T_SEQ * 64 * 4);
  unsigned short* xb    = (unsigned short*)alloc((size_t)M_ROWS * C_DIM * 2);
  unsigned short* wqkvb = (unsigned short*)alloc((size_t)QKV_N * C_DIM * 2);
  unsigned short* wob   = (unsigned short*)alloc((size_t)C_DIM * C_DIM * 2);
  unsigned short* qb    = (unsigned short*)alloc((size_t)M_ROWS * C_DIM * 2);
  unsigned short* ktil  = (unsigned short*)alloc((size_t)NB * NKV * 32 * KTILE * 2);
  unsigned short* vtil  = (unsigned short*)alloc((size_t)NB * NKV * 32 * KTILE * 2);
  unsigned short* attb  = (unsigned short*)alloc((size_t)M_ROWS * C_DIM * 2);

  dim3 blk(256);
  rope_tables<<<dim3(T_SEQ), dim3(64), 0, stream>>>(cost, sint);

  // bf16 conversions (wq|wk|wv concatenated -> fused QKV weight [3072][2048])
  cvt_f32_bf16<<<dim3(M_ROWS * C_DIM / 2048), blk, 0, stream>>>(x, xb, M_ROWS * C_DIM / 8);
  cvt_f32_bf16<<<dim3(C_DIM * C_DIM / 2048), blk, 0, stream>>>(wq, wqkvb, C_DIM * C_DIM / 8);
  cvt_f32_bf16<<<dim3(KV_DIM * C_DIM / 2048), blk, 0, stream>>>(
      wk, wqkvb + (size_t)C_DIM * C_DIM, KV_DIM * C_DIM / 8);
  cvt_f32_bf16<<<dim3(KV_DIM * C_DIM / 2048), blk, 0, stream>>>(
      wv, wqkvb + (size_t)(C_DIM + KV_DIM) * C_DIM, KV_DIM * C_DIM / 8);
  cvt_f32_bf16<<<dim3(C_DIM * C_DIM / 2048), blk, 0, stream>>>(wo, wob, C_DIM * C_DIM / 8);

  // Fused Q|K|V projection: 768 blocks = 3/CU
  gemm_lds_bf16<<<dim3(QKV_N / 128, M_ROWS / 128), blk, 0, stream>>>(
      xb, wqkvb, qkvp, M_ROWS, QKV_N, C_DIM);

  // RMSNorm + RoPE. Q: row-major bf16, scale folds 1/sqrt(HD) and log2(e).
  const float qscale = 0.08838834764831845f * 1.4426950408889634f;
  norm_rope_bf16<<<dim3(M_ROWS * NH / 4), blk, 0, stream>>>(
      qkvp, qb, qw, cost, sint, NH, QKV_N, C_DIM, qscale);
  // K: tiled layout for LDS staging
  norm_rope_k_tiled<<<dim3(M_ROWS * NKV / 4), blk, 0, stream>>>(
      qkvp + C_DIM, ktil, kw, cost, sint, QKV_N);

  // V -> tiled transposed bf16 (V^T)
  transpose_v<<<dim3(M_ROWS / 64, KV_DIM / 64), blk, 0, stream>>>(
      qkvp + C_DIM + KV_DIM, vtil, QKV_N);

  // Flash attention v7: 256 blocks x 8 waves (2/SIMD), mirror chunks concurrent
  attn_mfma6<<<dim3(256), dim3(512), 0, stream>>>(qb, ktil, vtil, attb);

  // Output projection
  gemm_lds_bf16<<<dim3(C_DIM / 128, M_ROWS / 128), blk, 0, stream>>>(
      attb, wob, out, M_ROWS, C_DIM, C_DIM);
}